// Round 8
// baseline (400.481 us; speedup 1.0000x reference)
//
#include <hip/hip_runtime.h>
#include <stdint.h>

// Problem constants (B=8, T=4096, Zc=512, D=256, K=8192)
#define M_TOT 32768
#define ZC 512
#define DD 256
#define KCODES 8192
#define NGRAN 512            // KCODES / 16 codes per granule
#define MARGIN 0.15f         // >2x hard fp16-error bound (validated R2/R3/R4)
#define NBUCKET 256

typedef _Float16 half8   __attribute__((ext_vector_type(8)));
typedef _Float16 half2v  __attribute__((ext_vector_type(2)));
typedef float    float4v __attribute__((ext_vector_type(4)));
typedef float    float16v __attribute__((ext_vector_type(16)));

// Workspace layout (bytes). wt_hi/wt_lo overlap smin: prep/gemm1 finish
// before k_dist writes smin (stream-ordered, every launch identical).
#define OFF_H     0ull                  // h fp32: 32 MB
#define OFF_HT    33554432ull           // ht fp16 tiled: 16 MB
#define OFF_CBT   50331648ull           // cbt fp16 tiled: 4 MB
#define OFF_HH    54525952ull           // hh: 128 KB
#define OFF_EE    54657024ull           // ee: 32 KB
#define OFF_LOSSP 54689792ull           // loss buckets: 1 KB
#define OFF_CNT   54690816ull           // select done-counter: 4 B
#define OFF_SMIN  54691840ull           // smin_T fp16 [NGRAN][M_TOT]: 32 MB
#define OFF_WTH   OFF_SMIN              // Wt_hi fp16 tiled: 512 KB (overlap)
#define OFF_WTL   (OFF_SMIN + 524288ull) // Wt_lo fp16 tiled: 512 KB (overlap)

// async global->LDS, 16B per lane, LDS dst = wave-uniform base + lane*16
#define ASYNC_CP16(gp, lp)                                                     \
  __builtin_amdgcn_global_load_lds(                                            \
      (const __attribute__((address_space(1))) void*)(gp),                     \
      (__attribute__((address_space(3))) void*)(lp), 16, 0, 0)

// ---------------------------------------------------------------------------
// Merged prep: W split-fp16 tiling (blocks 0..511) + codebook fp16 tiling /
// norms / loss-bucket + done-counter zero (blocks 512..2559).
// W tiled:  off(n,k) = ((n>>5)*64 + (k>>3))*256 + (n&31)*8 + (k&7)
// cb tiled: off(code,k) = ((code>>5)*32 + (k>>3))*256 + (code&31)*8 + (k&7)
// ---------------------------------------------------------------------------
__global__ __launch_bounds__(256) void k_prep(const float* __restrict__ W,
                                              const float* __restrict__ cb,
                                              _Float16* __restrict__ wt_hi,
                                              _Float16* __restrict__ wt_lo,
                                              _Float16* __restrict__ cbt,
                                              float* __restrict__ ee,
                                              float* __restrict__ loss_part,
                                              unsigned* __restrict__ cnt) {
    const int bx = blockIdx.x;
    if (bx < 512) {
        const int idx = bx * 256 + threadIdx.x;  // 131072
        const int n = idx & 255, k = idx >> 8;
        const float v = W[(size_t)k * DD + n];
        const _Float16 hi = (_Float16)v;
        const _Float16 lo = (_Float16)(v - (float)hi);
        const int off = (((n >> 5) * 64 + (k >> 3)) << 8) + ((n & 31) << 3) + (k & 7);
        wt_hi[off] = hi;
        wt_lo[off] = lo;
        return;
    }
    if (bx == 512) {
        loss_part[threadIdx.x] = 0.0f;
        if (threadIdx.x == 0) cnt[0] = 0u;
    }
    const int lane = threadIdx.x & 63, w = threadIdx.x >> 6;
    const int code = (bx - 512) * 4 + w;
    float4v v = *(const float4v*)&cb[(size_t)code * DD + lane * 4];
    half2v p0, p1;
    p0.x = (_Float16)v.x; p0.y = (_Float16)v.y;
    p1.x = (_Float16)v.z; p1.y = (_Float16)v.w;
    const size_t off = ((size_t)((code >> 5) * 32 + (lane >> 1)) << 8) +
                       ((code & 31) << 3) + ((lane & 1) << 2);
    *(half2v*)&cbt[off] = p0;
    *(half2v*)&cbt[off + 2] = p1;
    float s = v.x * v.x + v.y * v.y + v.z * v.z + v.w * v.w;
#pragma unroll
    for (int o = 32; o; o >>= 1) s += __shfl_down(s, o);
    if (lane == 0) ee[code] = s;
}

// ---------------------------------------------------------------------------
// K1 (R8): h = x@W + b via split-fp16 MFMA + fused prep_h epilogue.
// R8 change: output columns re-partitioned ACROSS all 4 waves (wave w owns
// cols w*64..w*64+63, nf in {0,1}) and BOTH m-halves (mh in {0,1}).
// Eliminates the R7 duplication where wy=0/wy=1 waves loaded identical
// bh/bl: per s-step now 4 global wt loads feed 12 MFMAs (was 8 loads / 12
// MFMAs with 2x cross-wave redundancy) -> gemm1 L2 wt traffic halves.
// Per-output accumulation order unchanged ((ah,bh),(ah,bl),(al,bh) over
// kb,s) -> h/ht bit-identical to R7. acc = 4 frags (64 regs), 4 chains
// interleaved (R6 lesson). hh partials now 4-way (sHHp[w][row]).
// ---------------------------------------------------------------------------
__global__ __launch_bounds__(256) void k_gemm1(const float* __restrict__ x,
                                               const _Float16* __restrict__ wt_hi,
                                               const _Float16* __restrict__ wt_lo,
                                               const float* __restrict__ b,
                                               float* __restrict__ h,
                                               _Float16* __restrict__ ht,
                                               float* __restrict__ hh) {
    __shared__ _Float16 sH[64 * 64];  // tiled [mblk2][kg8][32][8]
    __shared__ _Float16 sL[64 * 64];
    __shared__ _Float16 sT[64 * 256]; // 32KB fp16 transpose staging (swizzled)
    __shared__ float sHHp[4][64];
    const int tid = threadIdx.x, lane = tid & 63, w = tid >> 6;
    const int lw = lane & 31, csel = lane >> 5;
    const int m0 = blockIdx.x * 64;

    float16v a00 = (float16v)(0.f), a01 = (float16v)(0.f);  // [mh][nf]
    float16v a10 = (float16v)(0.f), a11 = (float16v)(0.f);

    for (int kb = 0; kb < ZC; kb += 64) {
        __syncthreads();
        {
            const int m = tid & 63;
            const int kp = tid >> 6;  // 0..3
#pragma unroll
            for (int i2 = 0; i2 < 2; ++i2) {
                const int kg = kp * 2 + i2;
                const float* src = x + (size_t)(m0 + m) * ZC + kb + kg * 8;
                float4v v0 = *(const float4v*)src;
                float4v v1 = *(const float4v*)(src + 4);
                half8 hi, lo;
                float vv[8] = {v0.x, v0.y, v0.z, v0.w, v1.x, v1.y, v1.z, v1.w};
#pragma unroll
                for (int j = 0; j < 8; ++j) {
                    hi[j] = (_Float16)vv[j];
                    lo[j] = (_Float16)(vv[j] - (float)hi[j]);
                }
                const int off = (((m >> 5) * 8 + kg) << 8) + ((m & 31) << 3);
                *(half8*)&sH[off] = hi;
                *(half8*)&sL[off] = lo;
            }
        }
        __syncthreads();
#pragma unroll
        for (int s = 0; s < 4; ++s) {
            const int S = (kb >> 4) + s;  // global k-step
            half8 ah0 = *(const half8*)&sH[((2 * s) << 8) + lane * 8];
            half8 al0 = *(const half8*)&sL[((2 * s) << 8) + lane * 8];
            half8 ah1 = *(const half8*)&sH[((8 + 2 * s) << 8) + lane * 8];
            half8 al1 = *(const half8*)&sL[((8 + 2 * s) << 8) + lane * 8];
            const size_t b0 = ((size_t)((w * 2 + 0) * 64 + 2 * S) << 8) + lane * 8;
            const size_t b1 = ((size_t)((w * 2 + 1) * 64 + 2 * S) << 8) + lane * 8;
            half8 bh0 = *(const half8*)&wt_hi[b0];
            half8 bl0 = *(const half8*)&wt_lo[b0];
            half8 bh1 = *(const half8*)&wt_hi[b1];
            half8 bl1 = *(const half8*)&wt_lo[b1];
            // 4 chains interleaved; per-acc order (ah,bh),(ah,bl),(al,bh).
            a00 = __builtin_amdgcn_mfma_f32_32x32x16_f16(ah0, bh0, a00, 0, 0, 0);
            a01 = __builtin_amdgcn_mfma_f32_32x32x16_f16(ah0, bh1, a01, 0, 0, 0);
            a10 = __builtin_amdgcn_mfma_f32_32x32x16_f16(ah1, bh0, a10, 0, 0, 0);
            a11 = __builtin_amdgcn_mfma_f32_32x32x16_f16(ah1, bh1, a11, 0, 0, 0);
            a00 = __builtin_amdgcn_mfma_f32_32x32x16_f16(ah0, bl0, a00, 0, 0, 0);
            a01 = __builtin_amdgcn_mfma_f32_32x32x16_f16(ah0, bl1, a01, 0, 0, 0);
            a10 = __builtin_amdgcn_mfma_f32_32x32x16_f16(ah1, bl0, a10, 0, 0, 0);
            a11 = __builtin_amdgcn_mfma_f32_32x32x16_f16(ah1, bl1, a11, 0, 0, 0);
            a00 = __builtin_amdgcn_mfma_f32_32x32x16_f16(al0, bh0, a00, 0, 0, 0);
            a01 = __builtin_amdgcn_mfma_f32_32x32x16_f16(al0, bh1, a01, 0, 0, 0);
            a10 = __builtin_amdgcn_mfma_f32_32x32x16_f16(al1, bh0, a10, 0, 0, 0);
            a11 = __builtin_amdgcn_mfma_f32_32x32x16_f16(al1, bh1, a11, 0, 0, 0);
        }
    }
    // ---- Fused epilogue. col = w*64 + nf*32 + lw; row = mh*32 + (r&3)+8*(r>>2)+4*csel.
    const float bias0 = b[w * 64 + lw];
    const float bias1 = b[w * 64 + 32 + lw];
#pragma unroll
    for (int mh = 0; mh < 2; ++mh) {
        const float16v* A0 = mh ? &a10 : &a00;
        const float16v* A1 = mh ? &a11 : &a01;
#pragma unroll
        for (int r = 0; r < 16; ++r) {
            const int row = mh * 32 + (r & 3) + 8 * (r >> 2) + 4 * csel;  // 0..63
            const int col0 = w * 64 + lw;
            const float v0 = (*A0)[r] + bias0;
            const float v1 = (*A1)[r] + bias1;
            h[(size_t)(m0 + row) * DD + col0] = v0;
            h[(size_t)(m0 + row) * DD + col0 + 32] = v1;
            sT[row * 256 + (col0 ^ ((row & 7) << 3))] = (_Float16)v0;
            sT[row * 256 + ((col0 + 32) ^ ((row & 7) << 3))] = (_Float16)v1;
            float p = v0 * v0 + v1 * v1;
#pragma unroll
            for (int o = 16; o; o >>= 1) p += __shfl_xor(p, o);  // 32 lw lanes
            if (lw == 0) sHHp[w][row] = p;  // lanes 0 & 32 write disjoint rows
        }
    }
    __syncthreads();
    // ht: 64-row slab = 32KB contiguous at ht + m0*256. j = chunk*32+rr;
    // chunk c = rb*32+kg; src row = rb*32+rr; dst = ht + m0*256 + j*8.
#pragma unroll
    for (int i = 0; i < 8; ++i) {
        const int j = tid + i * 256;
        const int c = j >> 5, rr = j & 31;
        const int row = (c >> 5) * 32 + rr, kg = c & 31;
        half8 v = *(const half8*)&sT[row * 256 + ((kg * 8) ^ ((row & 7) << 3))];
        *(half8*)&ht[(size_t)m0 * 256 + (size_t)j * 8] = v;
    }
    if (tid < 64)
        hh[m0 + tid] = (sHHp[0][tid] + sHHp[1][tid]) + (sHHp[2][tid] + sHHp[3][tid]);
}

// ---------------------------------------------------------------------------
// Phase 1 distance kernel — R6 (frozen): joint-nj FOUR-chain compute.
// R0-R6 history: counted-vmcnt dbuf / c=4 reuse / chunk-pipelining all
// neutral at ~51% MfmaUtil; 4-chain joint-nj = 126-128us @ 52-55% — the
// design's plateau (sum-of-pipes: MFMA ~58 + LDS ~41 + VALU ~25 ~= wall).
// Reuse up needs regs (kills occupancy via LDS/VGPR, R2); overlap up needs
// waves (register-bound at 2/SIMD). Frozen.
// ---------------------------------------------------------------------------
__global__ __launch_bounds__(256, 2) void k_dist(const _Float16* __restrict__ ht,
                                                 const _Float16* __restrict__ cbt,
                                                 const float* __restrict__ ee,
                                                 _Float16* __restrict__ smin) {
    __shared__ _Float16 sB[2][64 * 256];  // 2 x 32 KB, tiled [rowblk2][kg32][32][8]
    const int tid = threadIdx.x, lane = tid & 63, w = tid >> 6;
    const int lw = lane & 31, csel = lane >> 5;
    const int bx = blockIdx.x;  // 256-code split (32)
    const int by = blockIdx.y;  // 1024-row split (32)

    // Load A: 2 mfrags x 16 k-substeps, each half8 (codes in lanes&31).
    half8 afr[2][16];
    const size_t lo = (size_t)lane * 8;  // = csel*256 + lw*8 (kg = 2s+csel)
#pragma unroll
    for (int mi = 0; mi < 2; ++mi) {
        const _Float16* base = cbt + (size_t)(bx * 8 + w * 2 + mi) * 8192;
#pragma unroll
        for (int s = 0; s < 16; ++s)
            afr[mi][s] = *(const half8*)(base + s * 512 + lo);
    }
    // ee-folding ext frags
    half8 aext[2], bext;
#pragma unroll
    for (int j = 0; j < 8; ++j) bext[j] = (_Float16)0.f;
    if (csel == 0) bext[0] = (_Float16)(-0.5f);
#pragma unroll
    for (int mi = 0; mi < 2; ++mi) {
        const float e = ee[bx * 256 + w * 64 + mi * 32 + lw];
#pragma unroll
        for (int j = 0; j < 8; ++j) aext[mi][j] = (_Float16)0.f;
        if (csel == 0) aext[mi][0] = (_Float16)e;
    }

    // Staging: half-stage t = 64 rows = 32 KB; wave copies its 8 KB quarter
    // via 8 global_load_lds dwordx4 (wave-uniform LDS base + lane*16).
    const _Float16* hbase = ht + (size_t)by * 1024 * 256 + (size_t)w * 4096 + lane * 8;
#define STAGE_HS(buf, t)                                                       \
    do {                                                                       \
        const _Float16* g_ = hbase + (size_t)(t) * 16384;                      \
        char* l_ = (char*)&sB[(buf)][0] + w * 8192;                            \
        _Pragma("unroll")                                                      \
        for (int i_ = 0; i_ < 8; ++i_)                                         \
            ASYNC_CP16(g_ + i_ * 512, l_ + i_ * 1024);                         \
    } while (0)

    // B-fragment read: nj in {0,1}, s in {0..15}.
#define LDB(sb_, nj_, s_)                                                      \
    (*(const half8*)&(sb_)[(size_t)((((nj_) * 32) + 2 * (s_) + csel) << 8) + lw * 8])

    // Per-nj epilogue from two accumulators.
#define EPI(accA, accB, nj_)                                                   \
    do {                                                                       \
        float g0a = (accA)[0], g1a = (accA)[8];                                \
        float g0b = (accB)[0], g1b = (accB)[8];                                \
        _Pragma("unroll")                                                      \
        for (int r = 1; r < 8; ++r) {                                          \
            g0a = fmaxf(g0a, (accA)[r]);  g1a = fmaxf(g1a, (accA)[8 + r]);     \
            g0b = fmaxf(g0b, (accB)[r]);  g1b = fmaxf(g1b, (accB)[8 + r]);     \
        }                                                                      \
        g0a = fmaxf(g0a, __shfl_xor(g0a, 32));                                 \
        g1a = fmaxf(g1a, __shfl_xor(g1a, 32));                                 \
        g0b = fmaxf(g0b, __shfl_xor(g0b, 32));                                 \
        g1b = fmaxf(g1b, __shfl_xor(g1b, 32));                                 \
        if (lane < 32) {                                                       \
            const int row_ = r0_ + (nj_) * 32 + lane;                          \
            const int gb_ = bx * 16 + w * 4;                                   \
            smin[(size_t)(gb_ + 0) * M_TOT + row_] = (_Float16)(-2.f * g0a);   \
            smin[(size_t)(gb_ + 1) * M_TOT + row_] = (_Float16)(-2.f * g1a);   \
            smin[(size_t)(gb_ + 2) * M_TOT + row_] = (_Float16)(-2.f * g0b);   \
            smin[(size_t)(gb_ + 3) * M_TOT + row_] = (_Float16)(-2.f * g1b);   \
        }                                                                      \
    } while (0)

    // Compute one half-stage (64 rows): both njs jointly, 4 MFMA chains.
#define COMPUTE_HS(buf, t)                                                     \
    do {                                                                       \
        const int r0_ = by * 1024 + (t) * 64;                                  \
        const _Float16* sb_ = &sB[(buf)][0];                                   \
        float16v A00 = (float16v)(0.f), A01 = (float16v)(0.f);                 \
        float16v A10 = (float16v)(0.f), A11 = (float16v)(0.f);                 \
        __builtin_amdgcn_s_setprio(1);                                         \
        _Pragma("unroll")                                                      \
        for (int s = 0; s < 16; ++s) {                                         \
            half8 bf0 = LDB(sb_, 0, s);                                        \
            half8 bf1 = LDB(sb_, 1, s);                                        \
            A00 = __builtin_amdgcn_mfma_f32_32x32x16_f16(afr[0][s], bf0, A00, 0, 0, 0); \
            A01 = __builtin_amdgcn_mfma_f32_32x32x16_f16(afr[1][s], bf0, A01, 0, 0, 0); \
            A10 = __builtin_amdgcn_mfma_f32_32x32x16_f16(afr[0][s], bf1, A10, 0, 0, 0); \
            A11 = __builtin_amdgcn_mfma_f32_32x32x16_f16(afr[1][s], bf1, A11, 0, 0, 0); \
        }                                                                      \
        A00 = __builtin_amdgcn_mfma_f32_32x32x16_f16(aext[0], bext, A00, 0, 0, 0); \
        A01 = __builtin_amdgcn_mfma_f32_32x32x16_f16(aext[1], bext, A01, 0, 0, 0); \
        A10 = __builtin_amdgcn_mfma_f32_32x32x16_f16(aext[0], bext, A10, 0, 0, 0); \
        A11 = __builtin_amdgcn_mfma_f32_32x32x16_f16(aext[1], bext, A11, 0, 0, 0); \
        __builtin_amdgcn_s_setprio(0);                                         \
        EPI(A00, A01, 0);                                                      \
        EPI(A10, A11, 1);                                                      \
    } while (0)

    // Prologue: stage half-stages 0 and 1.
    STAGE_HS(0, 0);
    STAGE_HS(1, 1);
    // t=0: queue = [8 loads-0][8 loads-1] -> vmcnt(8) retires loads-0.
    asm volatile("s_waitcnt vmcnt(8)" ::: "memory");
    __builtin_amdgcn_s_barrier();
    __builtin_amdgcn_sched_barrier(0);
    COMPUTE_HS(0, 0);
    __builtin_amdgcn_sched_barrier(0);
    __builtin_amdgcn_s_barrier();

    // Steady state t=1..14: queue at wait =
    // [8 loads-t][8 stores-(t-1)][8 loads-(t+1)] -> vmcnt(16).
#pragma unroll 1
    for (int t = 1; t < 15; ++t) {
        const int cur = t & 1;
        STAGE_HS(cur ^ 1, t + 1);
        asm volatile("s_waitcnt vmcnt(16)" ::: "memory");  // loads-t landed
        __builtin_amdgcn_s_barrier();
        __builtin_amdgcn_sched_barrier(0);
        COMPUTE_HS(cur, t);
        __builtin_amdgcn_sched_barrier(0);
        __builtin_amdgcn_s_barrier();
    }
    // Tail t=15: queue = [8 loads-15][8 stores-14] -> vmcnt(8).
    asm volatile("s_waitcnt vmcnt(8)" ::: "memory");
    __builtin_amdgcn_s_barrier();
    __builtin_amdgcn_sched_barrier(0);
    COMPUTE_HS(1, 15);

#undef STAGE_HS
#undef COMPUTE_HS
#undef LDB
#undef EPI
}

// ---------------------------------------------------------------------------
// Phase 2 (R8): k_final folded in via last-block-done pattern. Scan logic
// verified R4: LDS-transpose 64-row slab of smin_T, margin-filter granules,
// exact fp32 rescore ((hh+ee)-2*dot, lowest-index tie-break), gather zq,
// write out, bucketized loss. Last block reduces loss buckets (read back
// via atomicAdd(p,0) to stay coherent across XCD L2s) and writes the loss.
// ---------------------------------------------------------------------------
__global__ __launch_bounds__(256, 2) void k_select(const float* __restrict__ h,
                                                   const float* __restrict__ cb,
                                                   const float* __restrict__ hh,
                                                   const float* __restrict__ ee,
                                                   const _Float16* __restrict__ smin,
                                                   float* __restrict__ out,
                                                   float* __restrict__ loss_part,
                                                   unsigned* __restrict__ cnt,
                                                   float* __restrict__ out_loss) {
    __shared__ _Float16 sS[64][512];  // [row][granule] = 64 KB
    const int t = threadIdx.x, lane = t & 63, w = t >> 6;
    const int r0 = blockIdx.x * 64;

    for (int gi = t; gi < NGRAN; gi += 256) {
        const _Float16* src = smin + (size_t)gi * M_TOT + r0;
#pragma unroll
        for (int c = 0; c < 8; ++c) {
            half8 v = *(const half8*)(src + c * 8);
#pragma unroll
            for (int j = 0; j < 8; ++j) sS[c * 8 + j][gi] = v[j];
        }
    }
    __syncthreads();

    float lossacc = 0.0f;
    for (int i = 0; i < 16; ++i) {
        const int row = r0 + w * 16 + i;
        float4v hv = *(const float4v*)&h[(size_t)row * DD + lane * 4];
        half8 sm = *(const half8*)&sS[w * 16 + i][lane * 8];
        float vmin = 1e30f;
        float sv[8];
#pragma unroll
        for (int j = 0; j < 8; ++j) {
            sv[j] = (float)sm[j];
            vmin = fminf(vmin, sv[j]);
        }
        float m2 = vmin;
#pragma unroll
        for (int o = 32; o; o >>= 1) m2 = fminf(m2, __shfl_xor(m2, o));
        const float thr = m2 + MARGIN;
        unsigned flags = 0;
#pragma unroll
        for (int j = 0; j < 8; ++j)
            if (sv[j] <= thr) flags |= (1u << j);

        unsigned long long act = __ballot(flags != 0);
        unsigned long long bestk = ~0ull;
        const float hhv = hh[row];
        while (act) {
            const int ln = __ffsll((long long)act) - 1;
            act &= act - 1;
            unsigned fl = (unsigned)__shfl((int)flags, ln);
            while (fl) {
                const int j = __ffs(fl) - 1;
                fl &= fl - 1;
                const int g = ln * 8 + j;
#pragma unroll
                for (int c = 0; c < 16; ++c) {
                    const int code = g * 16 + c;
                    float4v cv = *(const float4v*)&cb[(size_t)code * DD + lane * 4];
                    float s = hv.x * cv.x + hv.y * cv.y + hv.z * cv.z + hv.w * cv.w;
#pragma unroll
                    for (int o = 32; o; o >>= 1) s += __shfl_xor(s, o);
                    const float d = (hhv + ee[code]) - 2.0f * s;  // reference formula
                    const unsigned bts = __float_as_uint(d);
                    const unsigned mb =
                        bts ^ (unsigned)(((int)bts >> 31) | 0x80000000);
                    const unsigned long long key =
                        ((unsigned long long)mb << 32) | (unsigned)code;
                    if (key < bestk) bestk = key;
                }
            }
        }
        const unsigned best = (unsigned)(bestk & 0xffffffffull);
        float4v cv = *(const float4v*)&cb[(size_t)best * DD + lane * 4];
        *(float4v*)&out[(size_t)row * DD + lane * 4] = cv;
        const float dx = cv.x - hv.x, dy = cv.y - hv.y;
        const float dz = cv.z - hv.z, dw = cv.w - hv.w;
        lossacc += dx * dx + dy * dy + dz * dz + dw * dw;
    }
#pragma unroll
    for (int o = 32; o; o >>= 1) lossacc += __shfl_xor(lossacc, o);
    if (lane == 0)
        atomicAdd(&loss_part[(blockIdx.x * 4 + w) & (NBUCKET - 1)], lossacc);

    // ---- Last-block final reduction (replaces k_final launch).
    __threadfence();
    __shared__ unsigned sdone;
    if (t == 0) sdone = atomicAdd(cnt, 1u);
    __syncthreads();
    if (sdone == gridDim.x - 1) {
        float s = atomicAdd(&loss_part[t], 0.0f);  // coherent read
#pragma unroll
        for (int o = 32; o; o >>= 1) s += __shfl_down(s, o);
        __shared__ float wsum[4];
        if ((t & 63) == 0) wsum[t >> 6] = s;
        __syncthreads();
        if (t == 0)
            out_loss[0] = 1.25f * ((wsum[0] + wsum[1]) + (wsum[2] + wsum[3]))
                          / (float)(M_TOT * DD);  // BETA*mean + mean
    }
}

// ---------------------------------------------------------------------------
extern "C" void kernel_launch(void* const* d_in, const int* in_sizes, int n_in,
                              void* d_out, int out_size, void* d_ws, size_t ws_size,
                              hipStream_t stream) {
    const float* x  = (const float*)d_in[0];
    const float* W  = (const float*)d_in[1];
    const float* b  = (const float*)d_in[2];
    const float* cb = (const float*)d_in[3];
    float* out = (float*)d_out;

    char* ws = (char*)d_ws;
    float* h        = (float*)(ws + OFF_H);
    _Float16* ht    = (_Float16*)(ws + OFF_HT);
    _Float16* cbt   = (_Float16*)(ws + OFF_CBT);
    _Float16* wt_hi = (_Float16*)(ws + OFF_WTH);
    _Float16* wt_lo = (_Float16*)(ws + OFF_WTL);
    float* hh       = (float*)(ws + OFF_HH);
    float* ee       = (float*)(ws + OFF_EE);
    _Float16* smin  = (_Float16*)(ws + OFF_SMIN);
    float* loss_part = (float*)(ws + OFF_LOSSP);
    unsigned* cnt    = (unsigned*)(ws + OFF_CNT);

    hipLaunchKernelGGL(k_prep, dim3(512 + KCODES / 4), dim3(256), 0, stream,
                       W, cb, wt_hi, wt_lo, cbt, ee, loss_part, cnt);
    hipLaunchKernelGGL(k_gemm1, dim3(M_TOT / 64), dim3(256), 0, stream,
                       x, wt_hi, wt_lo, b, h, ht, hh);
    hipLaunchKernelGGL(k_dist, dim3(KCODES / 256, M_TOT / 1024), dim3(256),
                       0, stream, ht, cbt, ee, smin);
    hipLaunchKernelGGL(k_select, dim3(M_TOT / 64), dim3(256), 0, stream,
                       h, cb, hh, ee, smin, out, loss_part, cnt,
                       out + (size_t)M_TOT * DD);
}

// Round 10
// 374.761 us; speedup vs baseline: 1.0686x; 1.0686x over previous
//
#include <hip/hip_runtime.h>
#include <stdint.h>

// Problem constants (B=8, T=4096, Zc=512, D=256, K=8192)
// R10 == R9 resubmission (two consecutive container-acquisition failures;
// kernel never ran). Cosmetic-only diff for a fresh source hash.
#define M_TOT 32768
#define ZC 512
#define DD 256
#define KCODES 8192
#define NGRAN 512            // KCODES / 16 codes per granule
#define MARGIN 0.15f         // >2x hard fp16-error bound (validated R2/R3/R4)
#define NBUCKET 256

typedef _Float16 half8   __attribute__((ext_vector_type(8)));
typedef _Float16 half2v  __attribute__((ext_vector_type(2)));
typedef float    float4v __attribute__((ext_vector_type(4)));
typedef float    float16v __attribute__((ext_vector_type(16)));

// Workspace layout (bytes). wt_hi/wt_lo overlap smin: prep/gemm1 finish
// before k_dist writes smin (stream-ordered, every launch identical).
#define OFF_H     0ull                  // h fp32: 32 MB
#define OFF_HT    33554432ull           // ht fp16 tiled: 16 MB
#define OFF_CBT   50331648ull           // cbt fp16 tiled: 4 MB
#define OFF_HH    54525952ull           // hh: 128 KB
#define OFF_EE    54657024ull           // ee: 32 KB
#define OFF_LOSSP 54689792ull           // loss buckets: 1 KB
#define OFF_SMIN  54691840ull           // smin_T fp16 [NGRAN][M_TOT]: 32 MB
#define OFF_WTH   OFF_SMIN              // Wt_hi fp16 tiled: 512 KB (overlap)
#define OFF_WTL   (OFF_SMIN + 524288ull) // Wt_lo fp16 tiled: 512 KB (overlap)

// async global->LDS, 16B per lane, LDS dst = wave-uniform base + lane*16
#define ASYNC_CP16(gp, lp)                                                     \
  __builtin_amdgcn_global_load_lds(                                            \
      (const __attribute__((address_space(1))) void*)(gp),                     \
      (__attribute__((address_space(3))) void*)(lp), 16, 0, 0)

// ---------------------------------------------------------------------------
// Merged prep (R7-verified): W split-fp16 tiling (blocks 0..511) + codebook
// fp16 tiling / norms / loss-bucket zero (blocks 512..2559).
// W tiled:  off(n,k) = ((n>>5)*64 + (k>>3))*256 + (n&31)*8 + (k&7)
// cb tiled: off(code,k) = ((code>>5)*32 + (k>>3))*256 + (code&31)*8 + (k&7)
// ---------------------------------------------------------------------------
__global__ __launch_bounds__(256) void k_prep(const float* __restrict__ W,
                                              const float* __restrict__ cb,
                                              _Float16* __restrict__ wt_hi,
                                              _Float16* __restrict__ wt_lo,
                                              _Float16* __restrict__ cbt,
                                              float* __restrict__ ee,
                                              float* __restrict__ loss_part) {
    const int bx = blockIdx.x;
    if (bx < 512) {
        const int idx = bx * 256 + threadIdx.x;  // 131072
        const int n = idx & 255, k = idx >> 8;
        const float v = W[(size_t)k * DD + n];
        const _Float16 hi = (_Float16)v;
        const _Float16 lo = (_Float16)(v - (float)hi);
        const int off = (((n >> 5) * 64 + (k >> 3)) << 8) + ((n & 31) << 3) + (k & 7);
        wt_hi[off] = hi;
        wt_lo[off] = lo;
        return;
    }
    if (bx == 512) loss_part[threadIdx.x] = 0.0f;
    const int lane = threadIdx.x & 63, w = threadIdx.x >> 6;
    const int code = (bx - 512) * 4 + w;
    float4v v = *(const float4v*)&cb[(size_t)code * DD + lane * 4];
    half2v p0, p1;
    p0.x = (_Float16)v.x; p0.y = (_Float16)v.y;
    p1.x = (_Float16)v.z; p1.y = (_Float16)v.w;
    const size_t off = ((size_t)((code >> 5) * 32 + (lane >> 1)) << 8) +
                       ((code & 31) << 3) + ((lane & 1) << 2);
    *(half2v*)&cbt[off] = p0;
    *(half2v*)&cbt[off + 2] = p1;
    float s = v.x * v.x + v.y * v.y + v.z * v.z + v.w * v.w;
#pragma unroll
    for (int o = 32; o; o >>= 1) s += __shfl_down(s, o);
    if (lane == 0) ee[code] = s;
}

// ---------------------------------------------------------------------------
// K1 (R7-verified form): h = x@W + b via split-fp16 MFMA + fused prep_h
// epilogue (sT swizzled transpose, hh butterfly, coalesced ht stores).
// ---------------------------------------------------------------------------
__global__ __launch_bounds__(256) void k_gemm1(const float* __restrict__ x,
                                               const _Float16* __restrict__ wt_hi,
                                               const _Float16* __restrict__ wt_lo,
                                               const float* __restrict__ b,
                                               float* __restrict__ h,
                                               _Float16* __restrict__ ht,
                                               float* __restrict__ hh) {
    __shared__ _Float16 sH[64 * 64];  // tiled [mblk2][kg8][32][8]
    __shared__ _Float16 sL[64 * 64];
    __shared__ _Float16 sT[64 * 256]; // 32KB fp16 transpose staging (swizzled)
    __shared__ float sHH[64];
    const int tid = threadIdx.x, lane = tid & 63, w = tid >> 6;
    const int lw = lane & 31, csel = lane >> 5;
    const int wy = w >> 1, wx = w & 1;
    const int m0 = blockIdx.x * 64;

    float16v acc[4];
#pragma unroll
    for (int j = 0; j < 4; ++j) acc[j] = (float16v)(0.0f);

    for (int kb = 0; kb < ZC; kb += 64) {
        __syncthreads();
        {
            const int m = tid & 63;
            const int kp = tid >> 6;  // 0..3
#pragma unroll
            for (int i2 = 0; i2 < 2; ++i2) {
                const int kg = kp * 2 + i2;
                const float* src = x + (size_t)(m0 + m) * ZC + kb + kg * 8;
                float4v v0 = *(const float4v*)src;
                float4v v1 = *(const float4v*)(src + 4);
                half8 hi, lo;
                float vv[8] = {v0.x, v0.y, v0.z, v0.w, v1.x, v1.y, v1.z, v1.w};
#pragma unroll
                for (int j = 0; j < 8; ++j) {
                    hi[j] = (_Float16)vv[j];
                    lo[j] = (_Float16)(vv[j] - (float)hi[j]);
                }
                const int off = (((m >> 5) * 8 + kg) << 8) + ((m & 31) << 3);
                *(half8*)&sH[off] = hi;
                *(half8*)&sL[off] = lo;
            }
        }
        __syncthreads();
#pragma unroll
        for (int s = 0; s < 4; ++s) {
            const int S = (kb >> 4) + s;  // global k-step
            half8 ah = *(const half8*)&sH[((wy * 8 + 2 * s) << 8) + lane * 8];
            half8 al = *(const half8*)&sL[((wy * 8 + 2 * s) << 8) + lane * 8];
#pragma unroll
            for (int nf = 0; nf < 4; ++nf) {
                const int nblk = wx * 4 + nf;
                const size_t boff = ((size_t)(nblk * 64 + 2 * S) << 8) + lane * 8;
                half8 bh = *(const half8*)&wt_hi[boff];
                half8 bl = *(const half8*)&wt_lo[boff];
                acc[nf] = __builtin_amdgcn_mfma_f32_32x32x16_f16(ah, bh, acc[nf], 0, 0, 0);
                acc[nf] = __builtin_amdgcn_mfma_f32_32x32x16_f16(ah, bl, acc[nf], 0, 0, 0);
                acc[nf] = __builtin_amdgcn_mfma_f32_32x32x16_f16(al, bh, acc[nf], 0, 0, 0);
            }
        }
    }
    // ---- Fused epilogue. C layout: col=lane&31(+nf,wx), row=(r&3)+8*(r>>2)+4*csel.
    float bias[4];
#pragma unroll
    for (int nf = 0; nf < 4; ++nf) bias[nf] = b[wx * 128 + nf * 32 + lw];

    float pr[16];
    __syncthreads();
#pragma unroll
    for (int r = 0; r < 16; ++r) {
        const int row = wy * 32 + (r & 3) + 8 * (r >> 2) + 4 * csel;  // 0..63
        float p = 0.f;
#pragma unroll
        for (int nf = 0; nf < 4; ++nf) {
            const int col = wx * 128 + nf * 32 + lw;
            const float v = acc[nf][r] + bias[nf];
            h[(size_t)(m0 + row) * DD + col] = v;
            sT[row * 256 + (col ^ ((row & 7) << 3))] = (_Float16)v;
            p += v * v;
        }
#pragma unroll
        for (int o = 16; o; o >>= 1) p += __shfl_xor(p, o);  // sum over 32 lw lanes
        pr[r] = p;
        if (wx == 0 && lw == 0) sHH[row] = p;  // this wave's 128 cols
    }
    __syncthreads();
    if (wx == 1 && lw == 0) {
#pragma unroll
        for (int r = 0; r < 16; ++r) {
            const int row = wy * 32 + (r & 3) + 8 * (r >> 2) + 4 * csel;
            sHH[row] += pr[r];  // other 128 cols (rows disjoint across waves)
        }
    }
    __syncthreads();
    // ht: 64-row slab = 32KB contiguous at ht + m0*256.
#pragma unroll
    for (int i = 0; i < 8; ++i) {
        const int j = tid + i * 256;
        const int c = j >> 5, rr = j & 31;
        const int row = (c >> 5) * 32 + rr, kg = c & 31;
        half8 v = *(const half8*)&sT[row * 256 + ((kg * 8) ^ ((row & 7) << 3))];
        *(half8*)&ht[(size_t)m0 * 256 + (size_t)j * 8] = v;
    }
    if (tid < 64) hh[m0 + tid] = sHH[tid];
}

// ---------------------------------------------------------------------------
// Phase 1 distance kernel — R6 (frozen): joint-nj FOUR-chain compute.
// Plateau: sum-of-pipes (MFMA ~58 + LDS ~41 + VALU ~25 ~= 126-128us wall).
// ---------------------------------------------------------------------------
__global__ __launch_bounds__(256, 2) void k_dist(const _Float16* __restrict__ ht,
                                                 const _Float16* __restrict__ cbt,
                                                 const float* __restrict__ ee,
                                                 _Float16* __restrict__ smin) {
    __shared__ _Float16 sB[2][64 * 256];  // 2 x 32 KB, tiled [rowblk2][kg32][32][8]
    const int tid = threadIdx.x, lane = tid & 63, w = tid >> 6;
    const int lw = lane & 31, csel = lane >> 5;
    const int bx = blockIdx.x;  // 256-code split (32)
    const int by = blockIdx.y;  // 1024-row split (32)

    half8 afr[2][16];
    const size_t lo = (size_t)lane * 8;  // = csel*256 + lw*8 (kg = 2s+csel)
#pragma unroll
    for (int mi = 0; mi < 2; ++mi) {
        const _Float16* base = cbt + (size_t)(bx * 8 + w * 2 + mi) * 8192;
#pragma unroll
        for (int s = 0; s < 16; ++s)
            afr[mi][s] = *(const half8*)(base + s * 512 + lo);
    }
    half8 aext[2], bext;
#pragma unroll
    for (int j = 0; j < 8; ++j) bext[j] = (_Float16)0.f;
    if (csel == 0) bext[0] = (_Float16)(-0.5f);
#pragma unroll
    for (int mi = 0; mi < 2; ++mi) {
        const float e = ee[bx * 256 + w * 64 + mi * 32 + lw];
#pragma unroll
        for (int j = 0; j < 8; ++j) aext[mi][j] = (_Float16)0.f;
        if (csel == 0) aext[mi][0] = (_Float16)e;
    }

    const _Float16* hbase = ht + (size_t)by * 1024 * 256 + (size_t)w * 4096 + lane * 8;
#define STAGE_HS(buf, t)                                                       \
    do {                                                                       \
        const _Float16* g_ = hbase + (size_t)(t) * 16384;                      \
        char* l_ = (char*)&sB[(buf)][0] + w * 8192;                            \
        _Pragma("unroll")                                                      \
        for (int i_ = 0; i_ < 8; ++i_)                                         \
            ASYNC_CP16(g_ + i_ * 512, l_ + i_ * 1024);                         \
    } while (0)

#define LDB(sb_, nj_, s_)                                                      \
    (*(const half8*)&(sb_)[(size_t)((((nj_) * 32) + 2 * (s_) + csel) << 8) + lw * 8])

#define EPI(accA, accB, nj_)                                                   \
    do {                                                                       \
        float g0a = (accA)[0], g1a = (accA)[8];                                \
        float g0b = (accB)[0], g1b = (accB)[8];                                \
        _Pragma("unroll")                                                      \
        for (int r = 1; r < 8; ++r) {                                          \
            g0a = fmaxf(g0a, (accA)[r]);  g1a = fmaxf(g1a, (accA)[8 + r]);     \
            g0b = fmaxf(g0b, (accB)[r]);  g1b = fmaxf(g1b, (accB)[8 + r]);     \
        }                                                                      \
        g0a = fmaxf(g0a, __shfl_xor(g0a, 32));                                 \
        g1a = fmaxf(g1a, __shfl_xor(g1a, 32));                                 \
        g0b = fmaxf(g0b, __shfl_xor(g0b, 32));                                 \
        g1b = fmaxf(g1b, __shfl_xor(g1b, 32));                                 \
        if (lane < 32) {                                                       \
            const int row_ = r0_ + (nj_) * 32 + lane;                          \
            const int gb_ = bx * 16 + w * 4;                                   \
            smin[(size_t)(gb_ + 0) * M_TOT + row_] = (_Float16)(-2.f * g0a);   \
            smin[(size_t)(gb_ + 1) * M_TOT + row_] = (_Float16)(-2.f * g1a);   \
            smin[(size_t)(gb_ + 2) * M_TOT + row_] = (_Float16)(-2.f * g0b);   \
            smin[(size_t)(gb_ + 3) * M_TOT + row_] = (_Float16)(-2.f * g1b);   \
        }                                                                      \
    } while (0)

#define COMPUTE_HS(buf, t)                                                     \
    do {                                                                       \
        const int r0_ = by * 1024 + (t) * 64;                                  \
        const _Float16* sb_ = &sB[(buf)][0];                                   \
        float16v A00 = (float16v)(0.f), A01 = (float16v)(0.f);                 \
        float16v A10 = (float16v)(0.f), A11 = (float16v)(0.f);                 \
        __builtin_amdgcn_s_setprio(1);                                         \
        _Pragma("unroll")                                                      \
        for (int s = 0; s < 16; ++s) {                                         \
            half8 bf0 = LDB(sb_, 0, s);                                        \
            half8 bf1 = LDB(sb_, 1, s);                                        \
            A00 = __builtin_amdgcn_mfma_f32_32x32x16_f16(afr[0][s], bf0, A00, 0, 0, 0); \
            A01 = __builtin_amdgcn_mfma_f32_32x32x16_f16(afr[1][s], bf0, A01, 0, 0, 0); \
            A10 = __builtin_amdgcn_mfma_f32_32x32x16_f16(afr[0][s], bf1, A10, 0, 0, 0); \
            A11 = __builtin_amdgcn_mfma_f32_32x32x16_f16(afr[1][s], bf1, A11, 0, 0, 0); \
        }                                                                      \
        A00 = __builtin_amdgcn_mfma_f32_32x32x16_f16(aext[0], bext, A00, 0, 0, 0); \
        A01 = __builtin_amdgcn_mfma_f32_32x32x16_f16(aext[1], bext, A01, 0, 0, 0); \
        A10 = __builtin_amdgcn_mfma_f32_32x32x16_f16(aext[0], bext, A10, 0, 0, 0); \
        A11 = __builtin_amdgcn_mfma_f32_32x32x16_f16(aext[1], bext, A11, 0, 0, 0); \
        __builtin_amdgcn_s_setprio(0);                                         \
        EPI(A00, A01, 0);                                                      \
        EPI(A10, A11, 1);                                                      \
    } while (0)

    STAGE_HS(0, 0);
    STAGE_HS(1, 1);
    asm volatile("s_waitcnt vmcnt(8)" ::: "memory");
    __builtin_amdgcn_s_barrier();
    __builtin_amdgcn_sched_barrier(0);
    COMPUTE_HS(0, 0);
    __builtin_amdgcn_sched_barrier(0);
    __builtin_amdgcn_s_barrier();

#pragma unroll 1
    for (int t = 1; t < 15; ++t) {
        const int cur = t & 1;
        STAGE_HS(cur ^ 1, t + 1);
        asm volatile("s_waitcnt vmcnt(16)" ::: "memory");  // loads-t landed
        __builtin_amdgcn_s_barrier();
        __builtin_amdgcn_sched_barrier(0);
        COMPUTE_HS(cur, t);
        __builtin_amdgcn_sched_barrier(0);
        __builtin_amdgcn_s_barrier();
    }
    asm volatile("s_waitcnt vmcnt(8)" ::: "memory");
    __builtin_amdgcn_s_barrier();
    __builtin_amdgcn_sched_barrier(0);
    COMPUTE_HS(1, 15);

#undef STAGE_HS
#undef COMPUTE_HS
#undef LDB
#undef EPI
}

// ---------------------------------------------------------------------------
// Phase 2 (R9/R10): wave-per-row scan (verified R4) with 4-codes-parallel
// rescore. k_select is latency-bound (R8 profile: MfmaUtil 0, VALUBusy 16%,
// HBM 22%); the old rescore was strictly serial per code. New: 16-lane
// groups rescore 4 codes concurrently — lane L handles code
// g*16+q*4+(L>>4), dims (L&15)*16..+15; width-16 butterfly + 2 cross-group
// key-min steps. Same fp32 ops per dot (order-level rounding only), same
// min-key tie-break. R8's threadfence/last-block fold stays reverted.
// ---------------------------------------------------------------------------
__global__ __launch_bounds__(256, 2) void k_select(const float* __restrict__ h,
                                                   const float* __restrict__ cb,
                                                   const float* __restrict__ hh,
                                                   const float* __restrict__ ee,
                                                   const _Float16* __restrict__ smin,
                                                   float* __restrict__ out,
                                                   float* __restrict__ loss_part) {
    __shared__ _Float16 sS[64][512];  // [row][granule] = 64 KB
    const int t = threadIdx.x, lane = t & 63, w = t >> 6;
    const int r0 = blockIdx.x * 64;

    for (int gi = t; gi < NGRAN; gi += 256) {
        const _Float16* src = smin + (size_t)gi * M_TOT + r0;
#pragma unroll
        for (int c = 0; c < 8; ++c) {
            half8 v = *(const half8*)(src + c * 8);
#pragma unroll
            for (int j = 0; j < 8; ++j) sS[c * 8 + j][gi] = v[j];
        }
    }
    __syncthreads();

    float lossacc = 0.0f;
    for (int i = 0; i < 16; ++i) {
        const int row = r0 + w * 16 + i;
        float4v hv = *(const float4v*)&h[(size_t)row * DD + lane * 4];
        half8 sm = *(const half8*)&sS[w * 16 + i][lane * 8];
        float vmin = 1e30f;
        float sv[8];
#pragma unroll
        for (int j = 0; j < 8; ++j) {
            sv[j] = (float)sm[j];
            vmin = fminf(vmin, sv[j]);
        }
        float m2 = vmin;
#pragma unroll
        for (int o = 32; o; o >>= 1) m2 = fminf(m2, __shfl_xor(m2, o));
        const float thr = m2 + MARGIN;
        unsigned flags = 0;
#pragma unroll
        for (int j = 0; j < 8; ++j)
            if (sv[j] <= thr) flags |= (1u << j);

        // Rescore-layout row fragment: lane holds dims (lane&15)*16..+15.
        const float* hrp = &h[(size_t)row * DD + (lane & 15) * 16];
        float4v hr0 = *(const float4v*)hrp;
        float4v hr1 = *(const float4v*)(hrp + 4);
        float4v hr2 = *(const float4v*)(hrp + 8);
        float4v hr3 = *(const float4v*)(hrp + 12);

        unsigned long long act = __ballot(flags != 0);
        unsigned long long bestk = ~0ull;
        const float hhv = hh[row];
        while (act) {
            const int ln = __ffsll((long long)act) - 1;
            act &= act - 1;
            unsigned fl = (unsigned)__shfl((int)flags, ln);
            while (fl) {
                const int j = __ffs(fl) - 1;
                fl &= fl - 1;
                const int g = ln * 8 + j;
#pragma unroll
                for (int q = 0; q < 4; ++q) {
                    const int code = g * 16 + q * 4 + (lane >> 4);
                    const float* cp = &cb[(size_t)code * DD + (lane & 15) * 16];
                    float4v c0 = *(const float4v*)cp;
                    float4v c1 = *(const float4v*)(cp + 4);
                    float4v c2 = *(const float4v*)(cp + 8);
                    float4v c3 = *(const float4v*)(cp + 12);
                    float p = hr0.x * c0.x + hr0.y * c0.y + hr0.z * c0.z + hr0.w * c0.w
                            + hr1.x * c1.x + hr1.y * c1.y + hr1.z * c1.z + hr1.w * c1.w
                            + hr2.x * c2.x + hr2.y * c2.y + hr2.z * c2.z + hr2.w * c2.w
                            + hr3.x * c3.x + hr3.y * c3.y + hr3.z * c3.z + hr3.w * c3.w;
                    // width-16 butterfly: every lane of the group gets the dot
                    p += __shfl_xor(p, 1);
                    p += __shfl_xor(p, 2);
                    p += __shfl_xor(p, 4);
                    p += __shfl_xor(p, 8);
                    const float d = (hhv + ee[code]) - 2.0f * p;  // reference formula
                    const unsigned bts = __float_as_uint(d);
                    const unsigned mb =
                        bts ^ (unsigned)(((int)bts >> 31) | 0x80000000);
                    unsigned klo = (unsigned)code, khi = mb;
                    // cross-group key-min (xor 16, then 32): all lanes converge
#pragma unroll
                    for (int o = 16; o <= 32; o <<= 1) {
                        const unsigned olo = (unsigned)__shfl_xor((int)klo, o);
                        const unsigned ohi = (unsigned)__shfl_xor((int)khi, o);
                        if (ohi < khi || (ohi == khi && olo < klo)) {
                            khi = ohi; klo = olo;
                        }
                    }
                    const unsigned long long key =
                        ((unsigned long long)khi << 32) | klo;
                    if (key < bestk) bestk = key;
                }
            }
        }
        const unsigned best = (unsigned)(bestk & 0xffffffffull);
        float4v cv = *(const float4v*)&cb[(size_t)best * DD + lane * 4];
        *(float4v*)&out[(size_t)row * DD + lane * 4] = cv;
        const float dx = cv.x - hv.x, dy = cv.y - hv.y;
        const float dz = cv.z - hv.z, dw = cv.w - hv.w;
        lossacc += dx * dx + dy * dy + dz * dz + dw * dw;
    }
#pragma unroll
    for (int o = 32; o; o >>= 1) lossacc += __shfl_xor(lossacc, o);
    if (lane == 0)
        atomicAdd(&loss_part[(blockIdx.x * 4 + w) & (NBUCKET - 1)], lossacc);
}

__global__ __launch_bounds__(256) void k_final(const float* __restrict__ loss_part,
                                               float* __restrict__ out) {
    const int t = threadIdx.x;
    float s = loss_part[t];
#pragma unroll
    for (int off = 32; off; off >>= 1) s += __shfl_down(s, off);
    __shared__ float wsum[4];
    if ((t & 63) == 0) wsum[t >> 6] = s;
    __syncthreads();
    if (t == 0)
        out[0] = 1.25f * ((wsum[0] + wsum[1]) + (wsum[2] + wsum[3]))
                 / (float)(M_TOT * DD);  // BETA*mean + mean
}

// ---------------------------------------------------------------------------
extern "C" void kernel_launch(void* const* d_in, const int* in_sizes, int n_in,
                              void* d_out, int out_size, void* d_ws, size_t ws_size,
                              hipStream_t stream) {
    const float* x  = (const float*)d_in[0];
    const float* W  = (const float*)d_in[1];
    const float* b  = (const float*)d_in[2];
    const float* cb = (const float*)d_in[3];
    float* out = (float*)d_out;

    char* ws = (char*)d_ws;
    float* h        = (float*)(ws + OFF_H);
    _Float16* ht    = (_Float16*)(ws + OFF_HT);
    _Float16* cbt   = (_Float16*)(ws + OFF_CBT);
    _Float16* wt_hi = (_Float16*)(ws + OFF_WTH);
    _Float16* wt_lo = (_Float16*)(ws + OFF_WTL);
    float* hh       = (float*)(ws + OFF_HH);
    float* ee       = (float*)(ws + OFF_EE);
    _Float16* smin  = (_Float16*)(ws + OFF_SMIN);
    float* loss_part = (float*)(ws + OFF_LOSSP);

    hipLaunchKernelGGL(k_prep, dim3(512 + KCODES / 4), dim3(256), 0, stream,
                       W, cb, wt_hi, wt_lo, cbt, ee, loss_part);
    hipLaunchKernelGGL(k_gemm1, dim3(M_TOT / 64), dim3(256), 0, stream,
                       x, wt_hi, wt_lo, b, h, ht, hh);
    hipLaunchKernelGGL(k_dist, dim3(KCODES / 256, M_TOT / 1024), dim3(256),
                       0, stream, ht, cbt, ee, smin);
    hipLaunchKernelGGL(k_select, dim3(M_TOT / 64), dim3(256), 0, stream,
                       h, cb, hh, ee, smin, out, loss_part);
    hipLaunchKernelGGL(k_final, dim3(1), dim3(256), 0, stream,
                       loss_part, out + (size_t)M_TOT * DD);
}

// Round 11
// 351.354 us; speedup vs baseline: 1.1398x; 1.0666x over previous
//
#include <hip/hip_runtime.h>
#include <stdint.h>

// Problem constants (B=8, T=4096, Zc=512, D=256, K=8192)
#define M_TOT 32768
#define ZC 512
#define DD 256
#define KCODES 8192
#define NGRAN 512            // KCODES / 16 codes per granule
#define MARGIN 0.15f         // >2x hard fp16-error bound (validated R2/R3/R4)
#define NBUCKET 256
#define SSTRIDE 520          // sS row stride (halves): 1040 B, 16B-aligned

typedef _Float16 half8   __attribute__((ext_vector_type(8)));
typedef _Float16 half2v  __attribute__((ext_vector_type(2)));
typedef float    float4v __attribute__((ext_vector_type(4)));
typedef float    float16v __attribute__((ext_vector_type(16)));

// Workspace layout (bytes). wt_hi/wt_lo overlap smin: prep/gemm1 finish
// before k_dist writes smin (stream-ordered, every launch identical).
#define OFF_H     0ull                  // h fp32: 32 MB
#define OFF_HT    33554432ull           // ht fp16 tiled: 16 MB
#define OFF_CBT   50331648ull           // cbt fp16 tiled: 4 MB
#define OFF_HH    54525952ull           // hh: 128 KB
#define OFF_EE    54657024ull           // ee: 32 KB
#define OFF_LOSSP 54689792ull           // loss buckets: 1 KB
#define OFF_SMIN  54691840ull           // smin_T fp16 [NGRAN][M_TOT]: 32 MB
#define OFF_WTH   OFF_SMIN              // Wt_hi fp16 tiled: 512 KB (overlap)
#define OFF_WTL   (OFF_SMIN + 524288ull) // Wt_lo fp16 tiled: 512 KB (overlap)

// async global->LDS, 16B per lane, LDS dst = wave-uniform base + lane*16
#define ASYNC_CP16(gp, lp)                                                     \
  __builtin_amdgcn_global_load_lds(                                            \
      (const __attribute__((address_space(1))) void*)(gp),                     \
      (__attribute__((address_space(3))) void*)(lp), 16, 0, 0)

// ---------------------------------------------------------------------------
// Merged prep (R7-verified): W split-fp16 tiling (blocks 0..511) + codebook
// fp16 tiling / norms / loss-bucket zero (blocks 512..2559).
// W tiled:  off(n,k) = ((n>>5)*64 + (k>>3))*256 + (n&31)*8 + (k&7)
// cb tiled: off(code,k) = ((code>>5)*32 + (k>>3))*256 + (code&31)*8 + (k&7)
// ---------------------------------------------------------------------------
__global__ __launch_bounds__(256) void k_prep(const float* __restrict__ W,
                                              const float* __restrict__ cb,
                                              _Float16* __restrict__ wt_hi,
                                              _Float16* __restrict__ wt_lo,
                                              _Float16* __restrict__ cbt,
                                              float* __restrict__ ee,
                                              float* __restrict__ loss_part) {
    const int bx = blockIdx.x;
    if (bx < 512) {
        const int idx = bx * 256 + threadIdx.x;  // 131072
        const int n = idx & 255, k = idx >> 8;
        const float v = W[(size_t)k * DD + n];
        const _Float16 hi = (_Float16)v;
        const _Float16 lo = (_Float16)(v - (float)hi);
        const int off = (((n >> 5) * 64 + (k >> 3)) << 8) + ((n & 31) << 3) + (k & 7);
        wt_hi[off] = hi;
        wt_lo[off] = lo;
        return;
    }
    if (bx == 512) loss_part[threadIdx.x] = 0.0f;
    const int lane = threadIdx.x & 63, w = threadIdx.x >> 6;
    const int code = (bx - 512) * 4 + w;
    float4v v = *(const float4v*)&cb[(size_t)code * DD + lane * 4];
    half2v p0, p1;
    p0.x = (_Float16)v.x; p0.y = (_Float16)v.y;
    p1.x = (_Float16)v.z; p1.y = (_Float16)v.w;
    const size_t off = ((size_t)((code >> 5) * 32 + (lane >> 1)) << 8) +
                       ((code & 31) << 3) + ((lane & 1) << 2);
    *(half2v*)&cbt[off] = p0;
    *(half2v*)&cbt[off + 2] = p1;
    float s = v.x * v.x + v.y * v.y + v.z * v.z + v.w * v.w;
#pragma unroll
    for (int o = 32; o; o >>= 1) s += __shfl_down(s, o);
    if (lane == 0) ee[code] = s;
}

// ---------------------------------------------------------------------------
// K1 (R7-verified form): h = x@W + b via split-fp16 MFMA + fused prep_h
// epilogue (sT swizzled transpose, hh butterfly, coalesced ht stores).
// ---------------------------------------------------------------------------
__global__ __launch_bounds__(256) void k_gemm1(const float* __restrict__ x,
                                               const _Float16* __restrict__ wt_hi,
                                               const _Float16* __restrict__ wt_lo,
                                               const float* __restrict__ b,
                                               float* __restrict__ h,
                                               _Float16* __restrict__ ht,
                                               float* __restrict__ hh) {
    __shared__ _Float16 sH[64 * 64];  // tiled [mblk2][kg8][32][8]
    __shared__ _Float16 sL[64 * 64];
    __shared__ _Float16 sT[64 * 256]; // 32KB fp16 transpose staging (swizzled)
    __shared__ float sHH[64];
    const int tid = threadIdx.x, lane = tid & 63, w = tid >> 6;
    const int lw = lane & 31, csel = lane >> 5;
    const int wy = w >> 1, wx = w & 1;
    const int m0 = blockIdx.x * 64;

    float16v acc[4];
#pragma unroll
    for (int j = 0; j < 4; ++j) acc[j] = (float16v)(0.0f);

    for (int kb = 0; kb < ZC; kb += 64) {
        __syncthreads();
        {
            const int m = tid & 63;
            const int kp = tid >> 6;  // 0..3
#pragma unroll
            for (int i2 = 0; i2 < 2; ++i2) {
                const int kg = kp * 2 + i2;
                const float* src = x + (size_t)(m0 + m) * ZC + kb + kg * 8;
                float4v v0 = *(const float4v*)src;
                float4v v1 = *(const float4v*)(src + 4);
                half8 hi, lo;
                float vv[8] = {v0.x, v0.y, v0.z, v0.w, v1.x, v1.y, v1.z, v1.w};
#pragma unroll
                for (int j = 0; j < 8; ++j) {
                    hi[j] = (_Float16)vv[j];
                    lo[j] = (_Float16)(vv[j] - (float)hi[j]);
                }
                const int off = (((m >> 5) * 8 + kg) << 8) + ((m & 31) << 3);
                *(half8*)&sH[off] = hi;
                *(half8*)&sL[off] = lo;
            }
        }
        __syncthreads();
#pragma unroll
        for (int s = 0; s < 4; ++s) {
            const int S = (kb >> 4) + s;  // global k-step
            half8 ah = *(const half8*)&sH[((wy * 8 + 2 * s) << 8) + lane * 8];
            half8 al = *(const half8*)&sL[((wy * 8 + 2 * s) << 8) + lane * 8];
#pragma unroll
            for (int nf = 0; nf < 4; ++nf) {
                const int nblk = wx * 4 + nf;
                const size_t boff = ((size_t)(nblk * 64 + 2 * S) << 8) + lane * 8;
                half8 bh = *(const half8*)&wt_hi[boff];
                half8 bl = *(const half8*)&wt_lo[boff];
                acc[nf] = __builtin_amdgcn_mfma_f32_32x32x16_f16(ah, bh, acc[nf], 0, 0, 0);
                acc[nf] = __builtin_amdgcn_mfma_f32_32x32x16_f16(ah, bl, acc[nf], 0, 0, 0);
                acc[nf] = __builtin_amdgcn_mfma_f32_32x32x16_f16(al, bh, acc[nf], 0, 0, 0);
            }
        }
    }
    // ---- Fused epilogue. C layout: col=lane&31(+nf,wx), row=(r&3)+8*(r>>2)+4*csel.
    float bias[4];
#pragma unroll
    for (int nf = 0; nf < 4; ++nf) bias[nf] = b[wx * 128 + nf * 32 + lw];

    float pr[16];
    __syncthreads();
#pragma unroll
    for (int r = 0; r < 16; ++r) {
        const int row = wy * 32 + (r & 3) + 8 * (r >> 2) + 4 * csel;  // 0..63
        float p = 0.f;
#pragma unroll
        for (int nf = 0; nf < 4; ++nf) {
            const int col = wx * 128 + nf * 32 + lw;
            const float v = acc[nf][r] + bias[nf];
            h[(size_t)(m0 + row) * DD + col] = v;
            sT[row * 256 + (col ^ ((row & 7) << 3))] = (_Float16)v;
            p += v * v;
        }
#pragma unroll
        for (int o = 16; o; o >>= 1) p += __shfl_xor(p, o);  // sum over 32 lw lanes
        pr[r] = p;
        if (wx == 0 && lw == 0) sHH[row] = p;  // this wave's 128 cols
    }
    __syncthreads();
    if (wx == 1 && lw == 0) {
#pragma unroll
        for (int r = 0; r < 16; ++r) {
            const int row = wy * 32 + (r & 3) + 8 * (r >> 2) + 4 * csel;
            sHH[row] += pr[r];  // other 128 cols (rows disjoint across waves)
        }
    }
    __syncthreads();
    // ht: 64-row slab = 32KB contiguous at ht + m0*256.
#pragma unroll
    for (int i = 0; i < 8; ++i) {
        const int j = tid + i * 256;
        const int c = j >> 5, rr = j & 31;
        const int row = (c >> 5) * 32 + rr, kg = c & 31;
        half8 v = *(const half8*)&sT[row * 256 + ((kg * 8) ^ ((row & 7) << 3))];
        *(half8*)&ht[(size_t)m0 * 256 + (size_t)j * 8] = v;
    }
    if (tid < 64) hh[m0 + tid] = sHH[tid];
}

// ---------------------------------------------------------------------------
// Phase 1 distance kernel — R6 (frozen): joint-nj FOUR-chain compute.
// Plateau: sum-of-pipes (MFMA ~58 + LDS ~41 + VALU ~25 ~= 126-128us wall).
// ---------------------------------------------------------------------------
__global__ __launch_bounds__(256, 2) void k_dist(const _Float16* __restrict__ ht,
                                                 const _Float16* __restrict__ cbt,
                                                 const float* __restrict__ ee,
                                                 _Float16* __restrict__ smin) {
    __shared__ _Float16 sB[2][64 * 256];  // 2 x 32 KB, tiled [rowblk2][kg32][32][8]
    const int tid = threadIdx.x, lane = tid & 63, w = tid >> 6;
    const int lw = lane & 31, csel = lane >> 5;
    const int bx = blockIdx.x;  // 256-code split (32)
    const int by = blockIdx.y;  // 1024-row split (32)

    half8 afr[2][16];
    const size_t lo = (size_t)lane * 8;  // = csel*256 + lw*8 (kg = 2s+csel)
#pragma unroll
    for (int mi = 0; mi < 2; ++mi) {
        const _Float16* base = cbt + (size_t)(bx * 8 + w * 2 + mi) * 8192;
#pragma unroll
        for (int s = 0; s < 16; ++s)
            afr[mi][s] = *(const half8*)(base + s * 512 + lo);
    }
    half8 aext[2], bext;
#pragma unroll
    for (int j = 0; j < 8; ++j) bext[j] = (_Float16)0.f;
    if (csel == 0) bext[0] = (_Float16)(-0.5f);
#pragma unroll
    for (int mi = 0; mi < 2; ++mi) {
        const float e = ee[bx * 256 + w * 64 + mi * 32 + lw];
#pragma unroll
        for (int j = 0; j < 8; ++j) aext[mi][j] = (_Float16)0.f;
        if (csel == 0) aext[mi][0] = (_Float16)e;
    }

    const _Float16* hbase = ht + (size_t)by * 1024 * 256 + (size_t)w * 4096 + lane * 8;
#define STAGE_HS(buf, t)                                                       \
    do {                                                                       \
        const _Float16* g_ = hbase + (size_t)(t) * 16384;                      \
        char* l_ = (char*)&sB[(buf)][0] + w * 8192;                            \
        _Pragma("unroll")                                                      \
        for (int i_ = 0; i_ < 8; ++i_)                                         \
            ASYNC_CP16(g_ + i_ * 512, l_ + i_ * 1024);                         \
    } while (0)

#define LDB(sb_, nj_, s_)                                                      \
    (*(const half8*)&(sb_)[(size_t)((((nj_) * 32) + 2 * (s_) + csel) << 8) + lw * 8])

#define EPI(accA, accB, nj_)                                                   \
    do {                                                                       \
        float g0a = (accA)[0], g1a = (accA)[8];                                \
        float g0b = (accB)[0], g1b = (accB)[8];                                \
        _Pragma("unroll")                                                      \
        for (int r = 1; r < 8; ++r) {                                          \
            g0a = fmaxf(g0a, (accA)[r]);  g1a = fmaxf(g1a, (accA)[8 + r]);     \
            g0b = fmaxf(g0b, (accB)[r]);  g1b = fmaxf(g1b, (accB)[8 + r]);     \
        }                                                                      \
        g0a = fmaxf(g0a, __shfl_xor(g0a, 32));                                 \
        g1a = fmaxf(g1a, __shfl_xor(g1a, 32));                                 \
        g0b = fmaxf(g0b, __shfl_xor(g0b, 32));                                 \
        g1b = fmaxf(g1b, __shfl_xor(g1b, 32));                                 \
        if (lane < 32) {                                                       \
            const int row_ = r0_ + (nj_) * 32 + lane;                          \
            const int gb_ = bx * 16 + w * 4;                                   \
            smin[(size_t)(gb_ + 0) * M_TOT + row_] = (_Float16)(-2.f * g0a);   \
            smin[(size_t)(gb_ + 1) * M_TOT + row_] = (_Float16)(-2.f * g1a);   \
            smin[(size_t)(gb_ + 2) * M_TOT + row_] = (_Float16)(-2.f * g0b);   \
            smin[(size_t)(gb_ + 3) * M_TOT + row_] = (_Float16)(-2.f * g1b);   \
        }                                                                      \
    } while (0)

#define COMPUTE_HS(buf, t)                                                     \
    do {                                                                       \
        const int r0_ = by * 1024 + (t) * 64;                                  \
        const _Float16* sb_ = &sB[(buf)][0];                                   \
        float16v A00 = (float16v)(0.f), A01 = (float16v)(0.f);                 \
        float16v A10 = (float16v)(0.f), A11 = (float16v)(0.f);                 \
        __builtin_amdgcn_s_setprio(1);                                         \
        _Pragma("unroll")                                                      \
        for (int s = 0; s < 16; ++s) {                                         \
            half8 bf0 = LDB(sb_, 0, s);                                        \
            half8 bf1 = LDB(sb_, 1, s);                                        \
            A00 = __builtin_amdgcn_mfma_f32_32x32x16_f16(afr[0][s], bf0, A00, 0, 0, 0); \
            A01 = __builtin_amdgcn_mfma_f32_32x32x16_f16(afr[1][s], bf0, A01, 0, 0, 0); \
            A10 = __builtin_amdgcn_mfma_f32_32x32x16_f16(afr[0][s], bf1, A10, 0, 0, 0); \
            A11 = __builtin_amdgcn_mfma_f32_32x32x16_f16(afr[1][s], bf1, A11, 0, 0, 0); \
        }                                                                      \
        A00 = __builtin_amdgcn_mfma_f32_32x32x16_f16(aext[0], bext, A00, 0, 0, 0); \
        A01 = __builtin_amdgcn_mfma_f32_32x32x16_f16(aext[1], bext, A01, 0, 0, 0); \
        A10 = __builtin_amdgcn_mfma_f32_32x32x16_f16(aext[0], bext, A10, 0, 0, 0); \
        A11 = __builtin_amdgcn_mfma_f32_32x32x16_f16(aext[1], bext, A11, 0, 0, 0); \
        __builtin_amdgcn_s_setprio(0);                                         \
        EPI(A00, A01, 0);                                                      \
        EPI(A10, A11, 1);                                                      \
    } while (0)

    STAGE_HS(0, 0);
    STAGE_HS(1, 1);
    asm volatile("s_waitcnt vmcnt(8)" ::: "memory");
    __builtin_amdgcn_s_barrier();
    __builtin_amdgcn_sched_barrier(0);
    COMPUTE_HS(0, 0);
    __builtin_amdgcn_sched_barrier(0);
    __builtin_amdgcn_s_barrier();

#pragma unroll 1
    for (int t = 1; t < 15; ++t) {
        const int cur = t & 1;
        STAGE_HS(cur ^ 1, t + 1);
        asm volatile("s_waitcnt vmcnt(16)" ::: "memory");  // loads-t landed
        __builtin_amdgcn_s_barrier();
        __builtin_amdgcn_sched_barrier(0);
        COMPUTE_HS(cur, t);
        __builtin_amdgcn_sched_barrier(0);
        __builtin_amdgcn_s_barrier();
    }
    asm volatile("s_waitcnt vmcnt(8)" ::: "memory");
    __builtin_amdgcn_s_barrier();
    __builtin_amdgcn_sched_barrier(0);
    COMPUTE_HS(1, 15);

#undef STAGE_HS
#undef COMPUTE_HS
#undef LDB
#undef EPI
}

// ---------------------------------------------------------------------------
// Phase 2 (R11): R7-verified scan+rescore (R10's parallel rescore REVERTED:
// +20us regression), with COALESCED transpose staging. Old staging: thread
// t read smin+gi*M_TOT (gi=t) -> consecutive lanes 64KB apart -> each half8
// load = 64 divergent transactions, 1024/wave. New: wave-uniform gi, lane l
// reads smin[gi][r0+l] (128 B contiguous, 1-2 transactions), writes
// sS[l][gi]. sS rows padded to 520 halves: keeps row base 16B-aligned for
// the ds_read_b128 scan reads (1040 % 16 == 0), write conflict ~8-way
// (260 dwords % 32 = 4) — bounded, vs the old divergent-read wall.
// sS contents identical; only fill order changes.
// ---------------------------------------------------------------------------
__global__ __launch_bounds__(256, 2) void k_select(const float* __restrict__ h,
                                                   const float* __restrict__ cb,
                                                   const float* __restrict__ hh,
                                                   const float* __restrict__ ee,
                                                   const _Float16* __restrict__ smin,
                                                   float* __restrict__ out,
                                                   float* __restrict__ loss_part) {
    __shared__ _Float16 sS[64][SSTRIDE];  // [row][granule], padded
    const int t = threadIdx.x, lane = t & 63, w = t >> 6;
    const int r0 = blockIdx.x * 64;

    // Coalesced staging: wave w handles granules w*128 .. w*128+127.
    {
        const _Float16* src = smin + (size_t)(w * 128) * M_TOT + r0 + lane;
#pragma unroll 8
        for (int k = 0; k < 128; ++k)
            sS[lane][w * 128 + k] = src[(size_t)k * M_TOT];
    }
    __syncthreads();

    float lossacc = 0.0f;
    for (int i = 0; i < 16; ++i) {
        const int row = r0 + w * 16 + i;
        float4v hv = *(const float4v*)&h[(size_t)row * DD + lane * 4];
        half8 sm = *(const half8*)&sS[w * 16 + i][lane * 8];
        float vmin = 1e30f;
        float sv[8];
#pragma unroll
        for (int j = 0; j < 8; ++j) {
            sv[j] = (float)sm[j];
            vmin = fminf(vmin, sv[j]);
        }
        float m2 = vmin;
#pragma unroll
        for (int o = 32; o; o >>= 1) m2 = fminf(m2, __shfl_xor(m2, o));
        const float thr = m2 + MARGIN;
        unsigned flags = 0;
#pragma unroll
        for (int j = 0; j < 8; ++j)
            if (sv[j] <= thr) flags |= (1u << j);

        unsigned long long act = __ballot(flags != 0);
        unsigned long long bestk = ~0ull;
        const float hhv = hh[row];
        while (act) {
            const int ln = __ffsll((long long)act) - 1;
            act &= act - 1;
            unsigned fl = (unsigned)__shfl((int)flags, ln);
            while (fl) {
                const int j = __ffs(fl) - 1;
                fl &= fl - 1;
                const int g = ln * 8 + j;
#pragma unroll
                for (int c = 0; c < 16; ++c) {
                    const int code = g * 16 + c;
                    float4v cv = *(const float4v*)&cb[(size_t)code * DD + lane * 4];
                    float s = hv.x * cv.x + hv.y * cv.y + hv.z * cv.z + hv.w * cv.w;
#pragma unroll
                    for (int o = 32; o; o >>= 1) s += __shfl_xor(s, o);
                    const float d = (hhv + ee[code]) - 2.0f * s;  // reference formula
                    const unsigned bts = __float_as_uint(d);
                    const unsigned mb =
                        bts ^ (unsigned)(((int)bts >> 31) | 0x80000000);
                    const unsigned long long key =
                        ((unsigned long long)mb << 32) | (unsigned)code;
                    if (key < bestk) bestk = key;
                }
            }
        }
        const unsigned best = (unsigned)(bestk & 0xffffffffull);
        float4v cv = *(const float4v*)&cb[(size_t)best * DD + lane * 4];
        *(float4v*)&out[(size_t)row * DD + lane * 4] = cv;
        const float dx = cv.x - hv.x, dy = cv.y - hv.y;
        const float dz = cv.z - hv.z, dw = cv.w - hv.w;
        lossacc += dx * dx + dy * dy + dz * dz + dw * dw;
    }
#pragma unroll
    for (int o = 32; o; o >>= 1) lossacc += __shfl_xor(lossacc, o);
    if (lane == 0)
        atomicAdd(&loss_part[(blockIdx.x * 4 + w) & (NBUCKET - 1)], lossacc);
}

__global__ __launch_bounds__(256) void k_final(const float* __restrict__ loss_part,
                                               float* __restrict__ out) {
    const int t = threadIdx.x;
    float s = loss_part[t];
#pragma unroll
    for (int off = 32; off; off >>= 1) s += __shfl_down(s, off);
    __shared__ float wsum[4];
    if ((t & 63) == 0) wsum[t >> 6] = s;
    __syncthreads();
    if (t == 0)
        out[0] = 1.25f * ((wsum[0] + wsum[1]) + (wsum[2] + wsum[3]))
                 / (float)(M_TOT * DD);  // BETA*mean + mean
}

// ---------------------------------------------------------------------------
extern "C" void kernel_launch(void* const* d_in, const int* in_sizes, int n_in,
                              void* d_out, int out_size, void* d_ws, size_t ws_size,
                              hipStream_t stream) {
    const float* x  = (const float*)d_in[0];
    const float* W  = (const float*)d_in[1];
    const float* b  = (const float*)d_in[2];
    const float* cb = (const float*)d_in[3];
    float* out = (float*)d_out;

    char* ws = (char*)d_ws;
    float* h        = (float*)(ws + OFF_H);
    _Float16* ht    = (_Float16*)(ws + OFF_HT);
    _Float16* cbt   = (_Float16*)(ws + OFF_CBT);
    _Float16* wt_hi = (_Float16*)(ws + OFF_WTH);
    _Float16* wt_lo = (_Float16*)(ws + OFF_WTL);
    float* hh       = (float*)(ws + OFF_HH);
    float* ee       = (float*)(ws + OFF_EE);
    _Float16* smin  = (_Float16*)(ws + OFF_SMIN);
    float* loss_part = (float*)(ws + OFF_LOSSP);

    hipLaunchKernelGGL(k_prep, dim3(512 + KCODES / 4), dim3(256), 0, stream,
                       W, cb, wt_hi, wt_lo, cbt, ee, loss_part);
    hipLaunchKernelGGL(k_gemm1, dim3(M_TOT / 64), dim3(256), 0, stream,
                       x, wt_hi, wt_lo, b, h, ht, hh);
    hipLaunchKernelGGL(k_dist, dim3(KCODES / 256, M_TOT / 1024), dim3(256),
                       0, stream, ht, cbt, ee, smin);
    hipLaunchKernelGGL(k_select, dim3(M_TOT / 64), dim3(256), 0, stream,
                       h, cb, hh, ee, smin, out, loss_part);
    hipLaunchKernelGGL(k_final, dim3(1), dim3(256), 0, stream,
                       loss_part, out + (size_t)M_TOT * DD);
}